// Round 1
// baseline (193.982 us; speedup 1.0000x reference)
//
#include <hip/hip_runtime.h>
#include <stdint.h>

// HashedInterpolator: 3D hash-grid trilinear interpolation (Instant-NGP style)
// position: (2^21, 3) f32 in [0,1); hash_table: (2^22, 4) f32; out: (2^21, 4) f32
//
// Hash: h = (c0*1 ^ c1*19349663 ^ c2*83492791) & (2^22-1)
//   (per-step %2^22 in the reference commutes with the XOR since mod-pow2 = bitmask)
// Weights (reference's convention): bit=0 -> frac = (pos - lower/128)*128,
//                                   bit=1 -> (upper/128 - pos)*128
// All the /grids and /size ops are exact power-of-two scalings in fp32, so we
// match the reference arithmetic bit-for-bit up to FMA/accumulation order.

#define HASH_MASK 0x3FFFFFu
#define P1 19349663u
#define P2 83492791u

__global__ __launch_bounds__(256) void hashed_interp_kernel(
    const float* __restrict__ pos,
    const float* __restrict__ table,
    float* __restrict__ out,
    int batch)
{
    int i = blockIdx.x * 256 + threadIdx.x;
    if (i >= batch) return;

    // position load (12 B/thread, contiguous across the wave)
    float px = pos[3 * (size_t)i + 0];
    float py = pos[3 * (size_t)i + 1];
    float pz = pos[3 * (size_t)i + 2];

    // lower grid corner
    int lx = (int)floorf(px * 128.0f);
    int ly = (int)floorf(py * 128.0f);
    int lz = (int)floorf(pz * 128.0f);

    const float inv = 1.0f / 128.0f;  // exact
    // coef[...,0] = (pos - lower/128) * 128   (weight when bit == 0)
    // coef[...,1] = ((lower+1)/128 - pos) * 128 (weight when bit == 1)
    float w0x = (px - (float)lx * inv) * 128.0f;
    float w1x = ((float)(lx + 1) * inv - px) * 128.0f;
    float w0y = (py - (float)ly * inv) * 128.0f;
    float w1y = ((float)(ly + 1) * inv - py) * 128.0f;
    float w0z = (pz - (float)lz * inv) * 128.0f;
    float w1z = ((float)(lz + 1) * inv - pz) * 128.0f;

    // per-dim hash contributions for bit=0 / bit=1
    uint32_t hx0 = (uint32_t)lx;              // prime = 1
    uint32_t hx1 = (uint32_t)(lx + 1);
    uint32_t hy0 = (uint32_t)ly * P1;
    uint32_t hy1 = (uint32_t)(ly + 1) * P1;
    uint32_t hz0 = (uint32_t)lz * P2;
    uint32_t hz1 = (uint32_t)(lz + 1) * P2;

    float acc0 = 0.f, acc1 = 0.f, acc2 = 0.f, acc3 = 0.f;

    // BIT_TABLE order: c = (bx,by,bz) with bx the slowest bit
#pragma unroll
    for (int c = 0; c < 8; ++c) {
        int bx = (c >> 2) & 1;
        int by = (c >> 1) & 1;
        int bz = c & 1;
        uint32_t h = ((bx ? hx1 : hx0) ^ (by ? hy1 : hy0) ^ (bz ? hz1 : hz0)) & HASH_MASK;
        const float4 v = *reinterpret_cast<const float4*>(table + (size_t)h * 4);
        float w = ((bx ? w1x : w0x) * (by ? w1y : w0y)) * (bz ? w1z : w0z);
        acc0 += v.x * w;
        acc1 += v.y * w;
        acc2 += v.z * w;
        acc3 += v.w * w;
    }

    reinterpret_cast<float4*>(out)[i] = make_float4(acc0, acc1, acc2, acc3);
}

extern "C" void kernel_launch(void* const* d_in, const int* in_sizes, int n_in,
                              void* d_out, int out_size, void* d_ws, size_t ws_size,
                              hipStream_t stream) {
    const float* pos   = (const float*)d_in[0];   // (2^21, 3)
    const float* table = (const float*)d_in[1];   // (2^22, 4)
    float* out = (float*)d_out;                   // (2^21, 4)

    int batch = in_sizes[0] / 3;
    int blocks = (batch + 255) / 256;
    hashed_interp_kernel<<<blocks, 256, 0, stream>>>(pos, table, out, batch);
}